// Round 1
// baseline (267.622 us; speedup 1.0000x reference)
//
#include <hip/hip_runtime.h>
#include <cstdint>
#include <cstddef>

// ---------------------------------------------------------------------------
// SelfAttnV2: x[4,2048,1024] fp32 -> QKV proj -> softmax(QK^T/32) V -> out proj
// Strategy: bf16 MFMA GEMMs (16x16x32), fp32 accum. All GEMMs in B^T layout
// (contraction along contiguous dim): pre-transpose W_qkv/W_out, write V
// transposed in QKV epilogue. Scores bf16 in ws, softmax'd in place.
// ---------------------------------------------------------------------------

typedef __bf16 bf16;
typedef __bf16 bf16x8 __attribute__((ext_vector_type(8)));
typedef __bf16 bf16x4 __attribute__((ext_vector_type(4)));
typedef float  f32x4  __attribute__((ext_vector_type(4)));

#define BM 128
#define BN 128
#define BK 32

__device__ __forceinline__ void gload_lds16(const bf16* g, bf16* l) {
  // async global->LDS, 16B per lane; lds dest is wave-uniform base + lane*16
  __builtin_amdgcn_global_load_lds(
      (const __attribute__((address_space(1))) unsigned int*)g,
      (__attribute__((address_space(3))) unsigned int*)l,
      16, 0, 0);
}

// fp32 -> bf16 bulk convert (vectorized, n % 4 == 0 guaranteed by caller sizes)
__global__ __launch_bounds__(256) void k_f32_to_bf16(const float* __restrict__ in,
                                                     bf16* __restrict__ out, long n) {
  long i = ((long)blockIdx.x * blockDim.x + threadIdx.x) * 4;
  if (i + 3 < n) {
    float4 v = *(const float4*)(in + i);
    bf16x4 o;
    o[0] = (bf16)v.x; o[1] = (bf16)v.y; o[2] = (bf16)v.z; o[3] = (bf16)v.w;
    *(bf16x4*)(out + i) = o;
  }
}

// tiled transpose + convert: out[c][r] = (bf16) in[r][c]; R,C multiples of 32
__global__ __launch_bounds__(256) void k_transpose(const float* __restrict__ in,
                                                   bf16* __restrict__ out,
                                                   int R, int C) {
  __shared__ float t[32][33];
  int c0 = blockIdx.x * 32, r0 = blockIdx.y * 32;
  int tx = threadIdx.x, ty = threadIdx.y;
  #pragma unroll
  for (int dy = 0; dy < 32; dy += 8)
    t[ty + dy][tx] = in[(size_t)(r0 + ty + dy) * C + c0 + tx];
  __syncthreads();
  #pragma unroll
  for (int dy = 0; dy < 32; dy += 8)
    out[(size_t)(c0 + ty + dy) * R + r0 + tx] = (bf16)t[tx][ty + dy];
}

// row softmax in place over bf16 scores: 8192 rows x 2048 cols, 1 block/row
__global__ __launch_bounds__(256) void k_softmax(bf16* __restrict__ S) {
  const int row = blockIdx.x;
  bf16* p = S + (size_t)row * 2048;
  const int tid = threadIdx.x;
  bf16x8 vin = *(const bf16x8*)(p + tid * 8);
  float x[8];
  float mx = -1e30f;
  #pragma unroll
  for (int i = 0; i < 8; ++i) { x[i] = (float)vin[i]; mx = fmaxf(mx, x[i]); }
  #pragma unroll
  for (int off = 32; off; off >>= 1) mx = fmaxf(mx, __shfl_down(mx, off));
  __shared__ float redm[4];
  if ((tid & 63) == 0) redm[tid >> 6] = mx;
  __syncthreads();
  mx = fmaxf(fmaxf(redm[0], redm[1]), fmaxf(redm[2], redm[3]));
  float s = 0.f;
  #pragma unroll
  for (int i = 0; i < 8; ++i) { x[i] = __expf(x[i] - mx); s += x[i]; }
  #pragma unroll
  for (int off = 32; off; off >>= 1) s += __shfl_down(s, off);
  __shared__ float reds[4];
  if ((tid & 63) == 0) reds[tid >> 6] = s;
  __syncthreads();
  s = reds[0] + reds[1] + reds[2] + reds[3];
  float inv = 1.0f / s;
  bf16x8 vo;
  #pragma unroll
  for (int i = 0; i < 8; ++i) vo[i] = (bf16)(x[i] * inv);
  *(bf16x8*)(p + tid * 8) = vo;
}

// ---------------------------------------------------------------------------
// B^T GEMM: C[m][n] = sum_k A[m][k]*B[n][k]  (both row-major, contraction on
// contiguous dim). 128x128 tile, BK=32, 256 threads = 4 waves in 2x2, each
// wave a 64x64 subtile = 4x4 frags of mfma_f32_16x16x32_bf16.
// MODE 0: QKV proj  (bias, split -> Q | K | V^T)
// MODE 1: scores    (scale, -> bf16 S)
// MODE 2: PV        (-> bf16 AO)
// MODE 3: out proj  (bias, -> fp32 d_out)
// ---------------------------------------------------------------------------
template <int MODE>
__global__ __launch_bounds__(256) void gemm_bt(
    const bf16* __restrict__ A, long sAz, int lda,
    const bf16* __restrict__ B, long sBz, int ldb,
    int K,
    bf16* __restrict__ p0, long sCz,
    bf16* __restrict__ p1, bf16* __restrict__ p2,
    float* __restrict__ fout,
    const float* __restrict__ bias,
    float scale) {
  __shared__ bf16 As[BM * BK];
  __shared__ bf16 Bs[BN * BK];
  const int tid = threadIdx.x;
  const int wv = tid >> 6, ln = tid & 63;
  const int m0 = blockIdx.x * BM, n0 = blockIdx.y * BN;
  const int z = blockIdx.z;
  A += (long)z * sAz;
  B += (long)z * sBz;

  const int wr = wv >> 1, wc = wv & 1;
  const int lr = ln & 15, lh = ln >> 4;

  f32x4 acc[4][4];
  #pragma unroll
  for (int i = 0; i < 4; ++i)
    #pragma unroll
    for (int j = 0; j < 4; ++j)
      acc[i][j] = f32x4{0.f, 0.f, 0.f, 0.f};

  for (int k0 = 0; k0 < K; k0 += BK) {
    // stage A and B tiles: 512 chunks of 16B each, 2 per thread per tile.
    #pragma unroll
    for (int j = 0; j < 2; ++j) {
      const int cbase = wv * 128 + j * 64;        // wave-uniform chunk base
      const int chunk = cbase + ln;
      const int row = chunk >> 2, c8 = (chunk & 3) << 3;
      gload_lds16(A + (size_t)(m0 + row) * lda + k0 + c8, As + (size_t)cbase * 8);
      gload_lds16(B + (size_t)(n0 + row) * ldb + k0 + c8, Bs + (size_t)cbase * 8);
    }
    __syncthreads();  // drains vmcnt before compute

    bf16x8 af[4], bfr[4];
    #pragma unroll
    for (int i = 0; i < 4; ++i)
      af[i] = *(const bf16x8*)&As[(size_t)(wr * 64 + i * 16 + lr) * BK + lh * 8];
    #pragma unroll
    for (int j = 0; j < 4; ++j)
      bfr[j] = *(const bf16x8*)&Bs[(size_t)(wc * 64 + j * 16 + lr) * BK + lh * 8];
    #pragma unroll
    for (int i = 0; i < 4; ++i)
      #pragma unroll
      for (int j = 0; j < 4; ++j)
        acc[i][j] = __builtin_amdgcn_mfma_f32_16x16x32_bf16(af[i], bfr[j], acc[i][j], 0, 0, 0);
    __syncthreads();
  }

  // epilogue: C/D layout (verified): col = lane&15, row = (lane>>4)*4 + reg
  #pragma unroll
  for (int i = 0; i < 4; ++i) {
    #pragma unroll
    for (int j = 0; j < 4; ++j) {
      #pragma unroll
      for (int r = 0; r < 4; ++r) {
        const int gm = m0 + wr * 64 + i * 16 + lh * 4 + r;
        const int gn = n0 + wc * 64 + j * 16 + lr;
        float v = acc[i][j][r];
        if constexpr (MODE == 0) {
          v += bias[gn];
          if (gn < 1024) {
            p0[(size_t)gm * 1024 + gn] = (bf16)v;                 // Q
          } else if (gn < 2048) {
            p1[(size_t)gm * 1024 + (gn - 1024)] = (bf16)v;        // K
          } else {
            const int b = gm >> 11, s = gm & 2047, h = gn - 2048; // V^T
            p2[((size_t)b * 1024 + h) * 2048 + s] = (bf16)v;
          }
        } else if constexpr (MODE == 1) {
          p0[(size_t)z * sCz + (size_t)gm * 2048 + gn] = (bf16)(v * scale);
        } else if constexpr (MODE == 2) {
          p0[(size_t)z * sCz + (size_t)gm * 1024 + gn] = (bf16)v;
        } else {
          fout[(size_t)gm * 1024 + gn] = v + bias[gn];
        }
      }
    }
  }
}

// ---------------------------------------------------------------------------
extern "C" void kernel_launch(void* const* d_in, const int* in_sizes, int n_in,
                              void* d_out, int out_size, void* d_ws, size_t ws_size,
                              hipStream_t stream) {
  const float* x    = (const float*)d_in[0];  // [4,2048,1024]
  const float* Wqkv = (const float*)d_in[1];  // [1024,3072]
  const float* bqkv = (const float*)d_in[2];  // [3072]
  const float* Wout = (const float*)d_in[3];  // [1024,1024]
  const float* bout = (const float*)d_in[4];  // [1024]
  float* out = (float*)d_out;                 // [4,2048,1024] fp32

  char* w = (char*)d_ws;
  bf16* Xb  = (bf16*)(w + 0);          // [8192][1024]        16 MiB
  bf16* WqT = (bf16*)(w + 16777216);   // [3072][1024]         6 MiB
  bf16* WoT = (bf16*)(w + 23068672);   // [1024][1024]         2 MiB
  bf16* Qb  = (bf16*)(w + 25165824);   // [8192][1024]        16 MiB
  bf16* Kb  = (bf16*)(w + 41943040);   // [8192][1024]        16 MiB
  bf16* VT  = (bf16*)(w + 58720256);   // [4][1024][2048]     16 MiB
  bf16* Sb  = (bf16*)(w + 75497472);   // [4][2048][2048]     32 MiB (S -> P in place)
  bf16* AO  = (bf16*)(w + 109051904);  // [8192][1024]        16 MiB
  // total 120 MiB

  k_f32_to_bf16<<<8192, 256, 0, stream>>>(x, Xb, 8388608L);
  dim3 tb(32, 8);
  k_transpose<<<dim3(3072 / 32, 1024 / 32), tb, 0, stream>>>(Wqkv, WqT, 1024, 3072);
  k_transpose<<<dim3(1024 / 32, 1024 / 32), tb, 0, stream>>>(Wout, WoT, 1024, 1024);

  // QKV: [8192,1024] x [1024,3072] -> Q,K,V^T (bias)
  gemm_bt<0><<<dim3(64, 24), 256, 0, stream>>>(
      Xb, 0L, 1024, WqT, 0L, 1024, 1024,
      Qb, 0L, Kb, VT, nullptr, bqkv, 1.0f);

  // scores: per batch  Q[2048,1024] x K^T -> S[2048,2048] * 1/32
  gemm_bt<1><<<dim3(16, 16, 4), 256, 0, stream>>>(
      Qb, 2048L * 1024, 1024, Kb, 2048L * 1024, 1024, 1024,
      Sb, 2048L * 2048, nullptr, nullptr, nullptr, nullptr, 0.03125f);

  // softmax rows in place (S -> P)
  k_softmax<<<8192, 256, 0, stream>>>(Sb);

  // PV: per batch  P[2048,2048] x V^T[1024,2048](B^T) -> AO[2048,1024]
  gemm_bt<2><<<dim3(16, 8, 4), 256, 0, stream>>>(
      Sb, 2048L * 2048, 2048, VT, 1024L * 2048, 2048, 2048,
      AO, 2048L * 1024, nullptr, nullptr, nullptr, nullptr, 1.0f);

  // out proj: [8192,1024] x [1024,1024] + b -> fp32 d_out
  gemm_bt<3><<<dim3(64, 8), 256, 0, stream>>>(
      AO, 0L, 1024, WoT, 0L, 1024, 1024,
      nullptr, 0L, nullptr, nullptr, out, bout, 1.0f);
}

// Round 2
// 227.154 us; speedup vs baseline: 1.1782x; 1.1782x over previous
//
#include <hip/hip_runtime.h>
#include <cstdint>
#include <cstddef>

// ---------------------------------------------------------------------------
// SelfAttnV2: x[4,2048,1024] fp32 -> QKV proj -> softmax(QK^T/32) V -> out proj
// bf16 MFMA GEMMs, fp32 accum. 256x128 tile, BK=64, 8 waves, 3-buffer LDS ring,
// per-phase interleave + counted vmcnt (T3+T4), LDS XOR swizzle (T2), setprio (T5).
// ---------------------------------------------------------------------------

typedef __bf16 bf16;
typedef __bf16 bf16x8 __attribute__((ext_vector_type(8)));
typedef __bf16 bf16x4 __attribute__((ext_vector_type(4)));
typedef float  f32x4  __attribute__((ext_vector_type(4)));

#define THREADS 512
#define BM 256
#define BN 128
#define BK 64
#define UNIT 8192          // elements per staging unit (128 rows x 64 k-cols)
#define BUFELS (3*UNIT)    // A0 + A1 + B per K-tile buffer
#define NBUF 3

__device__ __forceinline__ void gload_lds16(const bf16* g, bf16* l) {
  __builtin_amdgcn_global_load_lds(
      (const __attribute__((address_space(1))) unsigned int*)g,
      (__attribute__((address_space(3))) unsigned int*)l,
      16, 0, 0);
}

// Stage one 128x64 bf16 unit (16KB) from global (g0 = &M[row0][k0], leading dim ld)
// into LDS with chunk swizzle: chunk c holds global (row=c>>3, slot=(c&7)^(row&7)).
__device__ __forceinline__ void stage_unit(const bf16* g0, long ld, bf16* ldsu, int tid) {
  const int wv = tid >> 6;
  #pragma unroll
  for (int j = 0; j < 2; ++j) {
    const int c = j * 512 + tid;
    const int r = c >> 3;
    const int sg = (c & 7) ^ (r & 7);
    const int cb = j * 512 + (wv << 6);   // wave-uniform chunk base
    gload_lds16(g0 + (long)r * ld + sg * 8, ldsu + (size_t)cb * 8);
  }
}

// swizzled ds_read of one bf16x8 fragment: row r (0..127) in unit, k-slot s (0..7)
__device__ __forceinline__ bf16x8 rd_frag(const bf16* unitb, int r, int s) {
  return *(const bf16x8*)(unitb + (size_t)r * 64 + (size_t)((s ^ (r & 7)) * 8));
}

// ---------------------------------------------------------------------------
// GEMM body: C[m][n] = sum_k A[m][k]*B[n][k] (B^T layout, contraction contiguous)
// MODE 0: QKV (+bias, split -> Q | K | V row-major)   MODE 1: scores (*scale)
// MODE 2: PV -> bf16                                  MODE 3: out proj (+bias) fp32
// ---------------------------------------------------------------------------
template <int MODE>
__device__ __forceinline__ void gemm_body(
    const bf16* __restrict__ A, long sAz, int lda,
    const bf16* __restrict__ B, long sBz, int ldb, int K,
    bf16* __restrict__ p0, long sCz,
    bf16* __restrict__ p1, bf16* __restrict__ p2,
    float* __restrict__ fout, const float* __restrict__ bias, float scale) {
  __shared__ bf16 lds[NBUF * BUFELS];   // 144 KiB
  const int tid = threadIdx.x;
  const int wv = tid >> 6, ln = tid & 63;
  const int wr = wv >> 1, wc = wv & 1;        // wave grid 4(M) x 2(N), 64x64 each
  const int lr = ln & 15, lh = ln >> 4;
  const int m0 = blockIdx.x * BM, n0 = blockIdx.y * BN;
  const int z = blockIdx.z;
  A += (long)z * sAz;
  B += (long)z * sBz;
  const bf16* Ag = A + (long)m0 * lda;
  const bf16* Bg = B + (long)n0 * ldb;
  const int NT = K / BK;

  // -------- prologue: stage tiles 0 and 1 --------
  #pragma unroll
  for (int t = 0; t < 2; ++t) {
    bf16* bb = lds + t * BUFELS;
    stage_unit(Ag + t * BK, lda, bb, tid);
    stage_unit(Ag + (long)128 * lda + t * BK, lda, bb + UNIT, tid);
    stage_unit(Bg + t * BK, ldb, bb + 2 * UNIT, tid);
  }
  asm volatile("s_waitcnt vmcnt(6)" ::: "memory");  // tile 0 staged; tile 1 in flight
  __builtin_amdgcn_sched_barrier(0);
  __builtin_amdgcn_s_barrier();

  f32x4 acc[4][4];
  #pragma unroll
  for (int i = 0; i < 4; ++i)
    #pragma unroll
    for (int j = 0; j < 4; ++j)
      acc[i][j] = f32x4{0.f, 0.f, 0.f, 0.f};

  const int aru = (wr & 1) * 64;   // A row base within unit
  const int au  = wr >> 1;         // which A unit

  int buf = 0, nb = 2;
  for (int t = 0; t < NT; ++t) {
    const bf16* Au = lds + buf * BUFELS + au * UNIT;
    const bf16* Bu = lds + buf * BUFELS + 2 * UNIT;
    bf16* Pn = lds + nb * BUFELS;
    const bool pf = (t + 2 < NT);
    bf16x8 aF[2][2], bF[4][2];

    // ============ phase 1 (m-frags 0,1) ============
    #pragma unroll
    for (int i = 0; i < 2; ++i)
      #pragma unroll
      for (int ks = 0; ks < 2; ++ks)
        aF[i][ks] = rd_frag(Au, aru + i * 16 + lr, (ks << 2) + lh);
    #pragma unroll
    for (int nf = 0; nf < 4; ++nf)
      #pragma unroll
      for (int ks = 0; ks < 2; ++ks)
        bF[nf][ks] = rd_frag(Bu, wc * 64 + nf * 16 + lr, (ks << 2) + lh);
    if (pf) {
      stage_unit(Ag + (long)(t + 2) * BK, lda, Pn, tid);
      stage_unit(Ag + (long)128 * lda + (long)(t + 2) * BK, lda, Pn + UNIT, tid);
    }
    __builtin_amdgcn_s_barrier();
    asm volatile("s_waitcnt lgkmcnt(0)" ::: "memory");
    __builtin_amdgcn_sched_barrier(0);
    __builtin_amdgcn_s_setprio(1);
    #pragma unroll
    for (int i = 0; i < 2; ++i)
      #pragma unroll
      for (int nf = 0; nf < 4; ++nf)
        #pragma unroll
        for (int ks = 0; ks < 2; ++ks)
          acc[i][nf] = __builtin_amdgcn_mfma_f32_16x16x32_bf16(aF[i][ks], bF[nf][ks], acc[i][nf], 0, 0, 0);
    __builtin_amdgcn_s_setprio(0);
    __builtin_amdgcn_s_barrier();

    // ============ phase 2 (m-frags 2,3) ============
    #pragma unroll
    for (int i = 0; i < 2; ++i)
      #pragma unroll
      for (int ks = 0; ks < 2; ++ks)
        aF[i][ks] = rd_frag(Au, aru + 32 + i * 16 + lr, (ks << 2) + lh);
    if (pf) stage_unit(Bg + (long)(t + 2) * BK, ldb, Pn + 2 * UNIT, tid);
    __builtin_amdgcn_s_barrier();
    asm volatile("s_waitcnt lgkmcnt(0)" ::: "memory");
    __builtin_amdgcn_sched_barrier(0);
    __builtin_amdgcn_s_setprio(1);
    #pragma unroll
    for (int i = 0; i < 2; ++i)
      #pragma unroll
      for (int nf = 0; nf < 4; ++nf)
        #pragma unroll
        for (int ks = 0; ks < 2; ++ks)
          acc[2 + i][nf] = __builtin_amdgcn_mfma_f32_16x16x32_bf16(aF[i][ks], bF[nf][ks], acc[2 + i][nf], 0, 0, 0);
    __builtin_amdgcn_s_setprio(0);
    if (t + 1 < NT) {
      // counted wait: everything older than this tile's 6 prefetch loads done
      if (pf) asm volatile("s_waitcnt vmcnt(6)" ::: "memory");
      else    asm volatile("s_waitcnt vmcnt(0)" ::: "memory");
      __builtin_amdgcn_sched_barrier(0);
    }
    __builtin_amdgcn_s_barrier();

    buf = (buf == 2) ? 0 : buf + 1;
    nb  = (nb == 2) ? 0 : nb + 1;
  }

  // -------- epilogue: C/D layout col=lane&15, row=(lane>>4)*4+reg --------
  #pragma unroll
  for (int mf = 0; mf < 4; ++mf) {
    #pragma unroll
    for (int nf = 0; nf < 4; ++nf) {
      #pragma unroll
      for (int rg = 0; rg < 4; ++rg) {
        const int gm = m0 + wr * 64 + mf * 16 + lh * 4 + rg;
        const int gn = n0 + wc * 64 + nf * 16 + lr;
        float v = acc[mf][nf][rg];
        if constexpr (MODE == 0) {
          v += bias[gn];
          if (gn < 1024)       p0[(size_t)gm * 1024 + gn] = (bf16)v;          // Q
          else if (gn < 2048)  p1[(size_t)gm * 1024 + (gn - 1024)] = (bf16)v; // K
          else                 p2[(size_t)gm * 1024 + (gn - 2048)] = (bf16)v; // V (row-major)
        } else if constexpr (MODE == 1) {
          p0[(size_t)z * sCz + (size_t)gm * 2048 + gn] = (bf16)(v * scale);
        } else if constexpr (MODE == 2) {
          p0[(size_t)z * sCz + (size_t)gm * 1024 + gn] = (bf16)v;
        } else {
          fout[(size_t)gm * 1024 + gn] = v + bias[gn];
        }
      }
    }
  }
}

#define GEMM_ARGS const bf16* A, long sAz, int lda, const bf16* B, long sBz, int ldb, \
                  int K, bf16* p0, long sCz, bf16* p1, bf16* p2, float* fout,         \
                  const float* bias, float scale
__global__ __launch_bounds__(THREADS, 2) void gemm_qkv(GEMM_ARGS) {
  gemm_body<0>(A, sAz, lda, B, sBz, ldb, K, p0, sCz, p1, p2, fout, bias, scale);
}
__global__ __launch_bounds__(THREADS, 2) void gemm_sc(GEMM_ARGS) {
  gemm_body<1>(A, sAz, lda, B, sBz, ldb, K, p0, sCz, p1, p2, fout, bias, scale);
}
__global__ __launch_bounds__(THREADS, 2) void gemm_pv(GEMM_ARGS) {
  gemm_body<2>(A, sAz, lda, B, sBz, ldb, K, p0, sCz, p1, p2, fout, bias, scale);
}
__global__ __launch_bounds__(THREADS, 2) void gemm_out(GEMM_ARGS) {
  gemm_body<3>(A, sAz, lda, B, sBz, ldb, K, p0, sCz, p1, p2, fout, bias, scale);
}

// ---------------------------------------------------------------------------
__global__ __launch_bounds__(256) void k_f32_to_bf16(const float* __restrict__ in,
                                                     bf16* __restrict__ out, long n) {
  long i = ((long)blockIdx.x * blockDim.x + threadIdx.x) * 4;
  if (i + 3 < n) {
    float4 v = *(const float4*)(in + i);
    bf16x4 o;
    o[0] = (bf16)v.x; o[1] = (bf16)v.y; o[2] = (bf16)v.z; o[3] = (bf16)v.w;
    *(bf16x4*)(out + i) = o;
  }
}

// fp32 [R][C] -> bf16 [C][R]
__global__ __launch_bounds__(256) void k_transpose(const float* __restrict__ in,
                                                   bf16* __restrict__ out, int R, int C) {
  __shared__ float t[32][33];
  int c0 = blockIdx.x * 32, r0 = blockIdx.y * 32;
  int tx = threadIdx.x, ty = threadIdx.y;
  #pragma unroll
  for (int dy = 0; dy < 32; dy += 8)
    t[ty + dy][tx] = in[(size_t)(r0 + ty + dy) * C + c0 + tx];
  __syncthreads();
  #pragma unroll
  for (int dy = 0; dy < 32; dy += 8)
    out[(size_t)(c0 + ty + dy) * R + r0 + tx] = (bf16)t[tx][ty + dy];
}

// bf16 per-batch transpose: V[z][2048][1024] -> VT[z][1024][2048]
__global__ __launch_bounds__(256) void k_transpose_v(const bf16* __restrict__ in,
                                                     bf16* __restrict__ out) {
  __shared__ bf16 t[32][33];
  const int z = blockIdx.z;
  in  += (size_t)z * 2048 * 1024;
  out += (size_t)z * 1024 * 2048;
  int h0 = blockIdx.x * 32, s0 = blockIdx.y * 32;
  int tx = threadIdx.x, ty = threadIdx.y;
  #pragma unroll
  for (int dy = 0; dy < 32; dy += 8)
    t[ty + dy][tx] = in[(size_t)(s0 + ty + dy) * 1024 + h0 + tx];
  __syncthreads();
  #pragma unroll
  for (int dy = 0; dy < 32; dy += 8)
    out[(size_t)(h0 + ty + dy) * 2048 + s0 + tx] = t[tx][ty + dy];
}

// row softmax in place over bf16 scores: 8192 rows x 2048 cols
__global__ __launch_bounds__(256) void k_softmax(bf16* __restrict__ S) {
  const int row = blockIdx.x;
  bf16* p = S + (size_t)row * 2048;
  const int tid = threadIdx.x;
  bf16x8 vin = *(const bf16x8*)(p + tid * 8);
  float x[8];
  float mx = -1e30f;
  #pragma unroll
  for (int i = 0; i < 8; ++i) { x[i] = (float)vin[i]; mx = fmaxf(mx, x[i]); }
  #pragma unroll
  for (int off = 32; off; off >>= 1) mx = fmaxf(mx, __shfl_down(mx, off));
  __shared__ float redm[4];
  if ((tid & 63) == 0) redm[tid >> 6] = mx;
  __syncthreads();
  mx = fmaxf(fmaxf(redm[0], redm[1]), fmaxf(redm[2], redm[3]));
  float s = 0.f;
  #pragma unroll
  for (int i = 0; i < 8; ++i) { x[i] = __expf(x[i] - mx); s += x[i]; }
  #pragma unroll
  for (int off = 32; off; off >>= 1) s += __shfl_down(s, off);
  __shared__ float reds[4];
  if ((tid & 63) == 0) reds[tid >> 6] = s;
  __syncthreads();
  s = reds[0] + reds[1] + reds[2] + reds[3];
  float inv = 1.0f / s;
  bf16x8 vo;
  #pragma unroll
  for (int i = 0; i < 8; ++i) vo[i] = (bf16)(x[i] * inv);
  *(bf16x8*)(p + tid * 8) = vo;
}

// ---------------------------------------------------------------------------
extern "C" void kernel_launch(void* const* d_in, const int* in_sizes, int n_in,
                              void* d_out, int out_size, void* d_ws, size_t ws_size,
                              hipStream_t stream) {
  const float* x    = (const float*)d_in[0];
  const float* Wqkv = (const float*)d_in[1];
  const float* bqkv = (const float*)d_in[2];
  const float* Wout = (const float*)d_in[3];
  const float* bout = (const float*)d_in[4];
  float* out = (float*)d_out;

  char* w = (char*)d_ws;
  const size_t MB = 1ull << 20;
  bf16* Xb  = (bf16*)(w);             // 16MB; dead after QKV -> reused as VT
  bf16* WqT = (bf16*)(w + 16 * MB);   //  6MB
  bf16* WoT = (bf16*)(w + 22 * MB);   //  2MB
  bf16* Qb  = (bf16*)(w + 24 * MB);   // 16MB
  bf16* Kb  = (bf16*)(w + 40 * MB);   // 16MB
  bf16* Vb  = (bf16*)(w + 56 * MB);   // 16MB
  bf16* Sb  = (bf16*)(w + 72 * MB);   // 32MB (S -> P in place)
  bf16* AO  = (bf16*)(w + 104 * MB);  // 16MB  (total 120MB)
  bf16* VT  = Xb;

  k_f32_to_bf16<<<8192, 256, 0, stream>>>(x, Xb, 8388608L);
  dim3 tb(32, 8);
  k_transpose<<<dim3(96, 32), tb, 0, stream>>>(Wqkv, WqT, 1024, 3072);
  k_transpose<<<dim3(32, 32), tb, 0, stream>>>(Wout, WoT, 1024, 1024);

  // QKV: [8192,1024] x [1024,3072]^T(b) + bias -> Q,K,V
  gemm_qkv<<<dim3(32, 24), THREADS, 0, stream>>>(
      Xb, 0L, 1024, WqT, 0L, 1024, 1024, Qb, 0L, Kb, Vb, nullptr, bqkv, 1.0f);

  // V -> V^T (per batch)
  k_transpose_v<<<dim3(32, 64, 4), tb, 0, stream>>>(Vb, VT);

  // scores: per batch Q x K^T * 1/32
  gemm_sc<<<dim3(8, 16, 4), THREADS, 0, stream>>>(
      Qb, 2048L * 1024, 1024, Kb, 2048L * 1024, 1024, 1024,
      Sb, 2048L * 2048, nullptr, nullptr, nullptr, nullptr, 0.03125f);

  k_softmax<<<8192, 256, 0, stream>>>(Sb);

  // PV: per batch P[2048,2048] x VT[1024,2048](B^T) -> AO
  gemm_pv<<<dim3(8, 8, 4), THREADS, 0, stream>>>(
      Sb, 2048L * 2048, 2048, VT, 1024L * 2048, 2048, 2048,
      AO, 2048L * 1024, nullptr, nullptr, nullptr, nullptr, 1.0f);

  // out proj + bias -> fp32
  gemm_out<<<dim3(32, 8), THREADS, 0, stream>>>(
      AO, 0L, 1024, WoT, 0L, 1024, 1024,
      nullptr, 0L, nullptr, nullptr, out, bout, 1.0f);
}